// Round 1
// baseline (102.772 us; speedup 1.0000x reference)
//
#include <hip/hip_runtime.h>

// YOLO-style loss, 3 scales fused.
// Scales: s=(16,64,64,3,5), m=(16,32,32,3,5), l=(16,16,16,3,5); coords (16,150,4).
// Cells: s=196608, m=49152, l=12288 -> 768/192/48 blocks of 256. Each block is
// entirely within one (scale, batch) since cells-per-batch (12288/3072/768) are
// all multiples of 256.

#define N_GT 150
#define EPSF 1e-9f

__global__ __launch_bounds__(256) void yolo_loss_stage1(
    const float* __restrict__ s_out, const float* __restrict__ m_out,
    const float* __restrict__ l_out,
    const float* __restrict__ s_gt,  const float* __restrict__ m_gt,
    const float* __restrict__ l_gt,
    const float* __restrict__ s_co,  const float* __restrict__ m_co,
    const float* __restrict__ l_co,
    float* __restrict__ ws)
{
    __shared__ float4 gcor[N_GT];   // x1,y1,x2,y2
    __shared__ float  gar[N_GT];    // area
    __shared__ float  partial[4];

    const int bid = blockIdx.x;
    const int tid = threadIdx.x;

    const float* op; const float* gp; const float* cp;
    int cellIdx, cpb;
    if (bid < 768)      { op = s_out; gp = s_gt; cp = s_co; cellIdx = bid * 256 + tid;         cpb = 12288; }
    else if (bid < 960) { op = m_out; gp = m_gt; cp = m_co; cellIdx = (bid - 768) * 256 + tid; cpb = 3072;  }
    else                { op = l_out; gp = l_gt; cp = l_co; cellIdx = (bid - 960) * 256 + tid; cpb = 768;   }
    const int b = cellIdx / cpb;

    if (tid < N_GT) {
        // coords[b][tid][0:4]; offset b*600 floats (2400 B, 16B aligned), tid*16 B
        float4 c = *reinterpret_cast<const float4*>(cp + (size_t)b * 600 + tid * 4);
        float hw = 0.5f * c.z, hh = 0.5f * c.w;
        gcor[tid] = make_float4(c.x - hw, c.y - hh, c.x + hw, c.y + hh);
        gar[tid]  = c.z * c.w;
    }
    __syncthreads();

    const size_t off = (size_t)cellIdx * 5;
    const float px = op[off+0], py = op[off+1], pw = op[off+2], ph = op[off+3], pc = op[off+4];
    const float tx = gp[off+0], ty = gp[off+1], tw = gp[off+2], th = gp[off+3], tc = gp[off+4];

    // ---- DIoU(out_coord, gt_coord) ----
    const float phw = 0.5f * pw, phh = 0.5f * ph;
    const float px1 = px - phw, px2 = px + phw, py1 = py - phh, py2 = py + phh;
    const float thw = 0.5f * tw, thh = 0.5f * th;
    const float tx1 = tx - thw, tx2 = tx + thw, ty1 = ty - thh, ty2 = ty + thh;
    const float areaP = pw * ph, areaT = tw * th;

    float iw = fmaxf(fminf(px2, tx2) - fmaxf(px1, tx1), 0.0f);
    float ih = fmaxf(fminf(py2, ty2) - fmaxf(py1, ty1), 0.0f);
    float inter = iw * ih;
    float uni   = areaP + areaT - inter;
    float iou   = inter / (uni + EPSF);
    float dx = px - tx, dy = py - ty;
    float cd2 = dx * dx + dy * dy;
    float ew = fmaxf(px2, tx2) - fminf(px1, tx1);
    float eh = fmaxf(py2, ty2) - fminf(py1, ty1);
    float diag2 = ew * ew + eh * eh;
    float diou = iou - cd2 / (diag2 + EPSF);

    const float box_scale = areaT * (1.0f / (512.0f * 512.0f));
    const float giou_l = tc * (2.0f - box_scale) * (1.0f - diou);

    // ---- max_iou < 0.5 predicate over 150 gt boxes (division-free) ----
    // iou_n >= 0.5  <=>  2*inter >= union + eps  <=>  3*inter - (areaP + areaG) >= eps
    float best = -1e30f;
    #pragma unroll 10
    for (int n = 0; n < N_GT; ++n) {
        float4 g = gcor[n];
        float w = fmaxf(fminf(px2, g.z) - fmaxf(px1, g.x), 0.0f);
        float h = fmaxf(fminf(py2, g.w) - fmaxf(py1, g.y), 0.0f);
        float in2 = w * h;
        float sc = 3.0f * in2 - (areaP + gar[n]);
        best = fmaxf(best, sc);
    }
    const float background = (1.0f - tc) * ((best < EPSF) ? 1.0f : 0.0f);

    // ---- focal BCE conf loss ----
    const float pcc = fminf(fmaxf(pc, 1e-7f), 1.0f - 1e-7f);
    const float bce = -(tc * logf(pcc) + (1.0f - tc) * logf(1.0f - pcc));
    const float dfc = fabsf(tc - pc);
    const float focal = fabsf(tc - 0.75f) * dfc * dfc;
    const float conf_l = focal * (tc + background) * bce;

    float v = giou_l + conf_l;

    // ---- block reduction ----
    #pragma unroll
    for (int o = 32; o > 0; o >>= 1) v += __shfl_down(v, o);
    const int lane = tid & 63, wv = tid >> 6;
    if (lane == 0) partial[wv] = v;
    __syncthreads();
    if (tid == 0) ws[bid] = partial[0] + partial[1] + partial[2] + partial[3];
}

__global__ __launch_bounds__(256) void yolo_loss_stage2(
    const float* __restrict__ ws, float* __restrict__ out)
{
    float v = 0.0f;
    for (int i = threadIdx.x; i < 1008; i += 256) v += ws[i];
    #pragma unroll
    for (int o = 32; o > 0; o >>= 1) v += __shfl_down(v, o);
    __shared__ float p[4];
    if ((threadIdx.x & 63) == 0) p[threadIdx.x >> 6] = v;
    __syncthreads();
    if (threadIdx.x == 0) out[0] = (p[0] + p[1] + p[2] + p[3]) * (1.0f / 16.0f);
}

extern "C" void kernel_launch(void* const* d_in, const int* in_sizes, int n_in,
                              void* d_out, int out_size, void* d_ws, size_t ws_size,
                              hipStream_t stream) {
    const float* s_out = (const float*)d_in[0];
    const float* m_out = (const float*)d_in[1];
    const float* l_out = (const float*)d_in[2];
    const float* s_gt  = (const float*)d_in[3];
    const float* m_gt  = (const float*)d_in[4];
    const float* l_gt  = (const float*)d_in[5];
    const float* s_co  = (const float*)d_in[6];
    const float* m_co  = (const float*)d_in[7];
    const float* l_co  = (const float*)d_in[8];
    float* out = (float*)d_out;
    float* ws  = (float*)d_ws;

    yolo_loss_stage1<<<1008, 256, 0, stream>>>(
        s_out, m_out, l_out, s_gt, m_gt, l_gt, s_co, m_co, l_co, ws);
    yolo_loss_stage2<<<1, 256, 0, stream>>>(ws, out);
}

// Round 2
// 102.308 us; speedup vs baseline: 1.0045x; 1.0045x over previous
//
#include <hip/hip_runtime.h>

// YOLO-style loss, 3 scales fused.
// Scales: s=(16,64,64,3,5), m=(16,32,32,3,5), l=(16,16,16,3,5); coords (16,150,4).
// Cells: s=196608, m=49152, l=12288 -> 768/192/48 blocks of 256. Each block is
// entirely within one (scale, batch) since cells-per-batch (12288/3072/768) are
// all multiples of 256.

#define N_GT 150
#define EPSF 1e-9f

__global__ __launch_bounds__(256) void yolo_loss_stage1(
    const float* __restrict__ s_out, const float* __restrict__ m_out,
    const float* __restrict__ l_out,
    const float* __restrict__ s_gt,  const float* __restrict__ m_gt,
    const float* __restrict__ l_gt,
    const float* __restrict__ s_co,  const float* __restrict__ m_co,
    const float* __restrict__ l_co,
    float* __restrict__ ws)
{
    __shared__ float4 gcor[N_GT];   // x1,y1,x2,y2
    __shared__ float  gar[N_GT];    // area
    __shared__ float  partial[4];

    const int bid = blockIdx.x;
    const int tid = threadIdx.x;

    const float* op; const float* gp; const float* cp;
    int cellIdx, cpb;
    if (bid < 768)      { op = s_out; gp = s_gt; cp = s_co; cellIdx = bid * 256 + tid;         cpb = 12288; }
    else if (bid < 960) { op = m_out; gp = m_gt; cp = m_co; cellIdx = (bid - 768) * 256 + tid; cpb = 3072;  }
    else                { op = l_out; gp = l_gt; cp = l_co; cellIdx = (bid - 960) * 256 + tid; cpb = 768;   }
    // b is block-uniform by construction (cpb multiples of 256); make it scalar.
    const int b = __builtin_amdgcn_readfirstlane(cellIdx / cpb);

    if (tid < N_GT) {
        // coords[b][tid][0:4]; offset b*600 floats (2400 B, 16B aligned), tid*16 B
        float4 c = *reinterpret_cast<const float4*>(cp + (size_t)b * 600 + tid * 4);
        float hw = 0.5f * c.z, hh = 0.5f * c.w;
        gcor[tid] = make_float4(c.x - hw, c.y - hh, c.x + hw, c.y + hh);
        gar[tid]  = c.z * c.w;
    }
    __syncthreads();

    const size_t off = (size_t)cellIdx * 5;
    const float px = op[off+0], py = op[off+1], pw = op[off+2], ph = op[off+3], pc = op[off+4];
    const float tx = gp[off+0], ty = gp[off+1], tw = gp[off+2], th = gp[off+3], tc = gp[off+4];

    // ---- DIoU(out_coord, gt_coord) ----
    const float phw = 0.5f * pw, phh = 0.5f * ph;
    const float px1 = px - phw, px2 = px + phw, py1 = py - phh, py2 = py + phh;
    const float thw = 0.5f * tw, thh = 0.5f * th;
    const float tx1 = tx - thw, tx2 = tx + thw, ty1 = ty - thh, ty2 = ty + thh;
    const float areaP = pw * ph, areaT = tw * th;

    float iw = fmaxf(fminf(px2, tx2) - fmaxf(px1, tx1), 0.0f);
    float ih = fmaxf(fminf(py2, ty2) - fmaxf(py1, ty1), 0.0f);
    float inter = iw * ih;
    float uni   = areaP + areaT - inter;
    float iou   = inter / (uni + EPSF);
    float dx = px - tx, dy = py - ty;
    float cd2 = dx * dx + dy * dy;
    float ew = fmaxf(px2, tx2) - fminf(px1, tx1);
    float eh = fmaxf(py2, ty2) - fminf(py1, ty1);
    float diag2 = ew * ew + eh * eh;
    float diou = iou - cd2 / (diag2 + EPSF);

    const float box_scale = areaT * (1.0f / (512.0f * 512.0f));
    const float giou_l = tc * (2.0f - box_scale) * (1.0f - diou);

    // ---- max_iou < 0.5 predicate over 150 gt boxes (division-free) ----
    // iou_n >= 0.5  <=>  3*inter - (areaP + gar[n]) >= eps
    // areaP is thread-constant: track best = max_n(3*inter - gar[n]),
    // compare best < areaP + eps at the end.  (-1 VALU op/iter)
    float best = -1e30f;
    #pragma unroll 10
    for (int n = 0; n < N_GT; ++n) {
        float4 g = gcor[n];
        float w = fmaxf(fminf(px2, g.z) - fmaxf(px1, g.x), 0.0f);
        float h = fmaxf(fminf(py2, g.w) - fmaxf(py1, g.y), 0.0f);
        float t = __builtin_fmaf(w * h, 3.0f, -gar[n]);
        best = fmaxf(best, t);
    }
    const float background = (1.0f - tc) * ((best < areaP + EPSF) ? 1.0f : 0.0f);

    // ---- focal BCE conf loss (hardware log path; rel err ~1e-6, fine vs thr) ----
    const float pcc = fminf(fmaxf(pc, 1e-7f), 1.0f - 1e-7f);
    const float bce = -(tc * __logf(pcc) + (1.0f - tc) * __logf(1.0f - pcc));
    const float dfc = fabsf(tc - pc);
    const float focal = fabsf(tc - 0.75f) * dfc * dfc;
    const float conf_l = focal * (tc + background) * bce;

    float v = giou_l + conf_l;

    // ---- block reduction ----
    #pragma unroll
    for (int o = 32; o > 0; o >>= 1) v += __shfl_down(v, o);
    const int lane = tid & 63, wv = tid >> 6;
    if (lane == 0) partial[wv] = v;
    __syncthreads();
    if (tid == 0) ws[bid] = partial[0] + partial[1] + partial[2] + partial[3];
}

__global__ __launch_bounds__(256) void yolo_loss_stage2(
    const float* __restrict__ ws, float* __restrict__ out)
{
    float v = 0.0f;
    for (int i = threadIdx.x; i < 1008; i += 256) v += ws[i];
    #pragma unroll
    for (int o = 32; o > 0; o >>= 1) v += __shfl_down(v, o);
    __shared__ float p[4];
    if ((threadIdx.x & 63) == 0) p[threadIdx.x >> 6] = v;
    __syncthreads();
    if (threadIdx.x == 0) out[0] = (p[0] + p[1] + p[2] + p[3]) * (1.0f / 16.0f);
}

extern "C" void kernel_launch(void* const* d_in, const int* in_sizes, int n_in,
                              void* d_out, int out_size, void* d_ws, size_t ws_size,
                              hipStream_t stream) {
    const float* s_out = (const float*)d_in[0];
    const float* m_out = (const float*)d_in[1];
    const float* l_out = (const float*)d_in[2];
    const float* s_gt  = (const float*)d_in[3];
    const float* m_gt  = (const float*)d_in[4];
    const float* l_gt  = (const float*)d_in[5];
    const float* s_co  = (const float*)d_in[6];
    const float* m_co  = (const float*)d_in[7];
    const float* l_co  = (const float*)d_in[8];
    float* out = (float*)d_out;
    float* ws  = (float*)d_ws;

    yolo_loss_stage1<<<1008, 256, 0, stream>>>(
        s_out, m_out, l_out, s_gt, m_gt, l_gt, s_co, m_co, l_co, ws);
    yolo_loss_stage2<<<1, 256, 0, stream>>>(ws, out);
}